// Round 1
// baseline (273.774 us; speedup 1.0000x reference)
//
#include <hip/hip_runtime.h>
#include <math.h>

// SpatialSampler: B=256, A=64, k=64, P=32, BETA=0.1
// out = [places (33.55M f32) | sampled_points (33.55M f32)] = 268.4 MB
//   places[bp,j,k]  = h[bp,j] * v[bp,k]
//   sampled[bp,j,k] = 100*h[jmax]*v[kmax] at (jmax,kmax), else 0
//
// Fused single kernel: one block per bp (8192 blocks x 256 threads).
//  - per-wave redundant shuffle argmax (no LDS, no barriers)
//  - each block writes its two contiguous 16 KB tiles: 8 f4 stores/thread
//  - nontemporal stores: output is streamed once, never re-read
// Pure streaming-write bound: 268 MB stores -> ~45 us floor @ 6.3 TB/s.

#define BETA 0.1f
#define PLACES_ELEMS 33554432ull     // 256*32*64*64

typedef float vfloat4 __attribute__((ext_vector_type(4)));

__global__ __launch_bounds__(256) void fused_sampler(
    const float* __restrict__ x_cat,
    const float* __restrict__ noise,
    float* __restrict__ out)
{
    const int bp   = blockIdx.x;              // (b,p) pair, [0, 8192)
    const int tid  = threadIdx.x;             // [0, 256)
    const int lane = tid & 63;

    const float* __restrict__ xrow = x_cat + (size_t)bp * 128;
    const float* __restrict__ nrow = noise + (size_t)bp * 128;

    // ---- per-wave redundant argmax over j (h-channel) and k (v-channel) ----
    // Each of the 4 waves computes the same reduction; cheaper than LDS+barrier.
    const float h = xrow[lane];               // h[lane] of this bp
    const float v = xrow[64 + lane];          // v[lane]
    float lph = logf(h) + BETA * nrow[lane];
    float lpv = logf(v) + BETA * nrow[64 + lane];
    int   jh  = lane;
    int   jv  = lane;

    #pragma unroll
    for (int off = 32; off > 0; off >>= 1) {
        const float oh = __shfl_xor(lph, off, 64);
        const int   oi = __shfl_xor(jh,  off, 64);
        const float ov = __shfl_xor(lpv, off, 64);
        const int   oj = __shfl_xor(jv,  off, 64);
        if (oh > lph || (oh == lph && oi < jh)) { lph = oh; jh = oi; }
        if (ov > lpv || (ov == lpv && oj < jv)) { lpv = ov; jv = oj; }
    }
    // jh/jv now wave-uniform argmax indices (smallest index on exact ties)
    const float sval = 100.0f * __shfl(h, jh, 64) * __shfl(v, jv, 64);

    // ---- streaming writes: two contiguous 1024-f4 (16 KB) tiles ----
    vfloat4* __restrict__ pout = (vfloat4*)out + (size_t)bp * 1024;
    vfloat4* __restrict__ sout = (vfloat4*)(out + PLACES_ELEMS) + (size_t)bp * 1024;

    const int kjv  = jv >> 2;                 // which f4-column holds vmax
    const int mjv  = jv & 3;                  // element within that f4

    #pragma unroll
    for (int it = 0; it < 4; ++it) {
        const int u = tid + it * 256;         // f4 index within 4096-elem tile
        const int j = u >> 4;                 // row 0..63
        const int c = u & 15;                 // col quad 0..15

        const float   hj = xrow[j];                             // L1 broadcast
        const vfloat4 v4 = *(const vfloat4*)(xrow + 64 + 4 * c);// L1 hit
        const vfloat4 pval = hj * v4;
        __builtin_nontemporal_store(pval, pout + u);

        // sampled tile: zeros except the single (jh, jv) element.
        // Compile-time component writes only (runtime vector index -> scratch).
        vfloat4 sv = {0.f, 0.f, 0.f, 0.f};
        const bool hit = (j == jh) & (c == kjv);
        sv.x = (hit && mjv == 0) ? sval : 0.f;
        sv.y = (hit && mjv == 1) ? sval : 0.f;
        sv.z = (hit && mjv == 2) ? sval : 0.f;
        sv.w = (hit && mjv == 3) ? sval : 0.f;
        __builtin_nontemporal_store(sv, sout + u);
    }
}

extern "C" void kernel_launch(void* const* d_in, const int* in_sizes, int n_in,
                              void* d_out, int out_size, void* d_ws, size_t ws_size,
                              hipStream_t stream) {
    const float* x_cat = (const float*)d_in[0];
    const float* noise = (const float*)d_in[1];
    float* out = (float*)d_out;

    // One block per (b,p): 8192 blocks x 256 threads, 8 f4-stores per thread
    // = full 268.4 MB output in a single dispatch.
    fused_sampler<<<dim3(8192), dim3(256), 0, stream>>>(x_cat, noise, out);
}

// Round 2
// 271.618 us; speedup vs baseline: 1.0079x; 1.0079x over previous
//
#include <hip/hip_runtime.h>
#include <math.h>

// SpatialSampler: B=256, A=64, k=64, P=32, BETA=0.1
// out = [places (33.55M f32) | sampled_points (33.55M f32)] = 268.4 MB
//   places[bp,j,k]  = h[bp,j] * v[bp,k]
//   sampled[bp,j,k] = 100*h[jmax]*v[kmax] at (jmax,kmax), else 0
//
// One kernel, 16384 blocks x 256 threads, block-uniform role split:
//   blocks [0,8192):     places tile for bp = blockIdx.x
//                        (no argmax, no noise read; v4 hoisted; 4 fmul+store)
//   blocks [8192,16384): sampled tile for bp = blockIdx.x - 8192
//                        (per-wave shuffle argmax; near-all-zero stores)
// Plain (not nontemporal) dwordx4 stores — same path the harness's fill
// kernel drives at 6.3 TB/s on this very buffer. Each wave writes one
// contiguous 1 KB per store instruction, one stream per block.

#define BETA 0.1f
#define PLACES_ELEMS 33554432ull     // 256*32*64*64

typedef float vfloat4 __attribute__((ext_vector_type(4)));

__global__ __launch_bounds__(256) void fused_sampler(
    const float* __restrict__ x_cat,
    const float* __restrict__ noise,
    float* __restrict__ out)
{
    const int b   = blockIdx.x;
    const int tid = threadIdx.x;

    if (b < 8192) {
        // ---------------- places half: fill-kernel-shaped ----------------
        const int bp = b;
        const float* __restrict__ xrow = x_cat + (size_t)bp * 128;
        vfloat4* __restrict__ pout = (vfloat4*)out + (size_t)bp * 1024;

        const int c  = tid & 15;              // col quad 0..15 (constant/thread)
        const int j0 = tid >> 4;              // base row 0..15
        const vfloat4 v4 = *(const vfloat4*)(xrow + 64 + 4 * c);  // hoisted

        #pragma unroll
        for (int it = 0; it < 4; ++it) {
            const int j = j0 + 16 * it;       // row 0..63
            const float hj = xrow[j];         // L1 broadcast (16 lanes share)
            pout[j * 16 + c] = hj * v4;       // u = tid + 256*it: coalesced
        }
    } else {
        // ---------------- sampled half: argmax + sparse scatter ----------
        const int bp   = b - 8192;
        const int lane = tid & 63;
        const float* __restrict__ xrow = x_cat + (size_t)bp * 128;
        const float* __restrict__ nrow = noise + (size_t)bp * 128;

        const float h = xrow[lane];
        const float v = xrow[64 + lane];
        float lph = logf(h) + BETA * nrow[lane];
        float lpv = logf(v) + BETA * nrow[64 + lane];
        int   jh  = lane;
        int   jv  = lane;

        #pragma unroll
        for (int off = 32; off > 0; off >>= 1) {
            const float oh = __shfl_xor(lph, off, 64);
            const int   oi = __shfl_xor(jh,  off, 64);
            const float ov = __shfl_xor(lpv, off, 64);
            const int   oj = __shfl_xor(jv,  off, 64);
            if (oh > lph || (oh == lph && oi < jh)) { lph = oh; jh = oi; }
            if (ov > lpv || (ov == lpv && oj < jv)) { lpv = ov; jv = oj; }
        }
        // jh/jv now wave-uniform argmax indices
        const float sval = 100.0f * __shfl(h, jh, 64) * __shfl(v, jv, 64);

        vfloat4* __restrict__ sout =
            (vfloat4*)(out + PLACES_ELEMS) + (size_t)bp * 1024;
        const int kjv = jv >> 2;              // f4-column holding vmax
        const int mjv = jv & 3;               // element within that f4

        const int c  = tid & 15;
        const int j0 = tid >> 4;

        #pragma unroll
        for (int it = 0; it < 4; ++it) {
            const int j = j0 + 16 * it;
            // zeros except the single (jh, jv) element; compile-time
            // component writes only (runtime vector index -> scratch).
            const bool hit = (j == jh) & (c == kjv);
            vfloat4 sv;
            sv.x = (hit && mjv == 0) ? sval : 0.f;
            sv.y = (hit && mjv == 1) ? sval : 0.f;
            sv.z = (hit && mjv == 2) ? sval : 0.f;
            sv.w = (hit && mjv == 3) ? sval : 0.f;
            sout[j * 16 + c] = sv;            // coalesced dwordx4
        }
    }
}

extern "C" void kernel_launch(void* const* d_in, const int* in_sizes, int n_in,
                              void* d_out, int out_size, void* d_ws, size_t ws_size,
                              hipStream_t stream) {
    const float* x_cat = (const float*)d_in[0];
    const float* noise = (const float*)d_in[1];
    float* out = (float*)d_out;

    // blocks [0,8192): places tiles; blocks [8192,16384): sampled tiles.
    // 16384 blocks x 256 threads, 4 f4-stores each = full 268.4 MB output.
    fused_sampler<<<dim3(16384), dim3(256), 0, stream>>>(x_cat, noise, out);
}

// Round 3
// 267.404 us; speedup vs baseline: 1.0238x; 1.0158x over previous
//
#include <hip/hip_runtime.h>
#include <math.h>

// SpatialSampler: B=256, A=64, k=64, P=32, BETA=0.1
// out = [places (33.55M f32) | sampled_points (33.55M f32)] = 268.4 MB
//   places[bp,j,k]  = h[bp,j] * v[bp,k]
//   sampled[bp,j,k] = 100*h[jmax]*v[kmax] at (jmax,kmax), else 0
//
// Wave-owned tiles, fill-kernel-shaped: 4096 blocks x 256 threads =
// 16384 waves; wave w owns ONE contiguous 16 KB output tile.
//   waves [0,8192):     places tile bp = w   (17 hoisted L1 loads, then
//                       16 independent 1KB-contiguous dwordx4 stores/thread-run)
//   waves [8192,16384): sampled tile bp = w-8192 (one argmax preamble per
//                       16 KB tile, then 16 merged near-zero stores)
// vs round 2: 4x fewer workgroups, 4x more stores per thread, preamble
// amortized over 4x more bytes -> deeper store pipeline per wave.

#define BETA 0.1f
#define PLACES_ELEMS 33554432ull     // 256*32*64*64

typedef float vfloat4 __attribute__((ext_vector_type(4)));

__global__ __launch_bounds__(256) void fused_sampler(
    const float* __restrict__ x_cat,
    const float* __restrict__ noise,
    float* __restrict__ out)
{
    const int w    = blockIdx.x * 4 + (threadIdx.x >> 6);  // wave id [0,16384)
    const int lane = threadIdx.x & 63;
    const int c    = lane & 15;           // col quad 0..15
    const int j0   = lane >> 4;           // row phase 0..3

    if (w < 8192) {
        // ---------------- places tile: fill-shaped ----------------
        const int bp = w;
        const float* __restrict__ xrow = x_cat + (size_t)bp * 128;
        vfloat4* __restrict__ pout = (vfloat4*)out + (size_t)bp * 1024;

        const vfloat4 v4 = *(const vfloat4*)(xrow + 64 + 4 * c);
        // Hoist all 16 h loads (static indices, independent, L1/L2-resident)
        float h[16];
        #pragma unroll
        for (int r = 0; r < 16; ++r) h[r] = xrow[j0 + 4 * r];

        // 16 independent stores; addr = lane + 64*r: each wave instruction
        // covers a contiguous, aligned 1 KB; tile = contiguous 16 KB.
        #pragma unroll
        for (int r = 0; r < 16; ++r)
            pout[lane + 64 * r] = h[r] * v4;
    } else {
        // ---------------- sampled tile: one argmax per 16 KB ----------
        const int bp = w - 8192;
        const float* __restrict__ xrow = x_cat + (size_t)bp * 128;
        const float* __restrict__ nrow = noise + (size_t)bp * 128;

        const float h = xrow[lane];
        const float v = xrow[64 + lane];
        float lph = logf(h) + BETA * nrow[lane];
        float lpv = logf(v) + BETA * nrow[64 + lane];
        int   jh  = lane;
        int   jv  = lane;

        #pragma unroll
        for (int off = 32; off > 0; off >>= 1) {
            const float oh = __shfl_xor(lph, off, 64);
            const int   oi = __shfl_xor(jh,  off, 64);
            const float ov = __shfl_xor(lpv, off, 64);
            const int   oj = __shfl_xor(jv,  off, 64);
            if (oh > lph || (oh == lph && oi < jh)) { lph = oh; jh = oi; }
            if (ov > lpv || (ov == lpv && oj < jv)) { lpv = ov; jv = oj; }
        }
        // jh/jv wave-uniform argmax indices (smallest index on exact ties)
        const float sval = 100.0f * __shfl(h, jh, 64) * __shfl(v, jv, 64);

        vfloat4* __restrict__ sout =
            (vfloat4*)(out + PLACES_ELEMS) + (size_t)bp * 1024;
        const int kjv = jv >> 2;          // f4-column holding vmax
        const int mjv = jv & 3;           // element within that f4

        #pragma unroll
        for (int r = 0; r < 16; ++r) {
            const int j = j0 + 4 * r;     // row of this store (addr lane+64r)
            // zeros except the single (jh, jv) element; compile-time
            // component writes only (runtime vector index -> scratch).
            const bool hit = (j == jh) & (c == kjv);
            vfloat4 sv;
            sv.x = (hit && mjv == 0) ? sval : 0.f;
            sv.y = (hit && mjv == 1) ? sval : 0.f;
            sv.z = (hit && mjv == 2) ? sval : 0.f;
            sv.w = (hit && mjv == 3) ? sval : 0.f;
            sout[lane + 64 * r] = sv;
        }
    }
}

extern "C" void kernel_launch(void* const* d_in, const int* in_sizes, int n_in,
                              void* d_out, int out_size, void* d_ws, size_t ws_size,
                              hipStream_t stream) {
    const float* x_cat = (const float*)d_in[0];
    const float* noise = (const float*)d_in[1];
    float* out = (float*)d_out;

    // 4096 blocks x 256 threads = 16384 waves; wave w -> 16 KB tile w.
    // 16 dwordx4 stores per thread = full 268.4 MB output, one dispatch.
    fused_sampler<<<dim3(4096), dim3(256), 0, stream>>>(x_cat, noise, out);
}

// Round 4
// 262.893 us; speedup vs baseline: 1.0414x; 1.0172x over previous
//
#include <hip/hip_runtime.h>
#include <math.h>

// SpatialSampler: B=256, A=64, k=64, P=32, BETA=0.1
// out = [places (33.55M f32) | sampled_points (33.55M f32)] = 268.4 MB
//   places[bp,j,k]  = h[bp,j] * v[bp,k]
//   sampled[bp,j,k] = 100*h[jmax]*v[kmax] at (jmax,kmax), else 0
//
// Round 4: deeper store pipelines. 2048 blocks x 256 threads = 8192 waves;
// each wave owns TWO adjacent 16 KB tiles (32 KB contiguous, 32 dwordx4
// stores per thread), halving per-wave setup overhead vs round 3.
//   waves [0,4096):    places tiles bp = 2w, 2w+1
//   waves [4096,8192): sampled tiles bp = 2(w-4096), +1 (argmax per tile)
// Grid = 2048 blocks = 8 blocks/CU: exactly one full-occupancy residency
// round, fill-kernel-shaped long store runs.

#define BETA 0.1f
#define PLACES_ELEMS 33554432ull     // 256*32*64*64

typedef float vfloat4 __attribute__((ext_vector_type(4)));

__global__ __launch_bounds__(256) void fused_sampler(
    const float* __restrict__ x_cat,
    const float* __restrict__ noise,
    float* __restrict__ out)
{
    const int w    = blockIdx.x * 4 + (threadIdx.x >> 6);  // wave id [0,8192)
    const int lane = threadIdx.x & 63;
    const int c    = lane & 15;           // col quad 0..15
    const int j0   = lane >> 4;           // row phase 0..3

    if (w < 4096) {
        // ---------------- places: 2 tiles, 32 KB contiguous ----------------
        #pragma unroll
        for (int q = 0; q < 2; ++q) {
            const int bp = 2 * w + q;
            const float* __restrict__ xrow = x_cat + (size_t)bp * 128;
            vfloat4* __restrict__ pout = (vfloat4*)out + (size_t)bp * 1024;

            const vfloat4 v4 = *(const vfloat4*)(xrow + 64 + 4 * c);
            float h[16];
            #pragma unroll
            for (int r = 0; r < 16; ++r) h[r] = xrow[j0 + 4 * r];

            // 16 independent stores; addr = lane + 64*r: each wave
            // instruction covers a contiguous aligned 1 KB.
            #pragma unroll
            for (int r = 0; r < 16; ++r)
                pout[lane + 64 * r] = h[r] * v4;
        }
    } else {
        // ---------------- sampled: 2 tiles, argmax per tile ----------------
        #pragma unroll
        for (int q = 0; q < 2; ++q) {
            const int bp = 2 * (w - 4096) + q;
            const float* __restrict__ xrow = x_cat + (size_t)bp * 128;
            const float* __restrict__ nrow = noise + (size_t)bp * 128;

            const float h = xrow[lane];
            const float v = xrow[64 + lane];
            float lph = logf(h) + BETA * nrow[lane];
            float lpv = logf(v) + BETA * nrow[64 + lane];
            int   jh  = lane;
            int   jv  = lane;

            #pragma unroll
            for (int off = 32; off > 0; off >>= 1) {
                const float oh = __shfl_xor(lph, off, 64);
                const int   oi = __shfl_xor(jh,  off, 64);
                const float ov = __shfl_xor(lpv, off, 64);
                const int   oj = __shfl_xor(jv,  off, 64);
                if (oh > lph || (oh == lph && oi < jh)) { lph = oh; jh = oi; }
                if (ov > lpv || (ov == lpv && oj < jv)) { lpv = ov; jv = oj; }
            }
            // jh/jv wave-uniform argmax (smallest index on exact ties)
            const float sval = 100.0f * __shfl(h, jh, 64) * __shfl(v, jv, 64);

            vfloat4* __restrict__ sout =
                (vfloat4*)(out + PLACES_ELEMS) + (size_t)bp * 1024;
            const int kjv = jv >> 2;      // f4-column holding vmax
            const int mjv = jv & 3;       // element within that f4

            #pragma unroll
            for (int r = 0; r < 16; ++r) {
                const int j = j0 + 4 * r; // row of this store (addr lane+64r)
                const bool hit = (j == jh) & (c == kjv);
                // compile-time component writes only (runtime index->scratch)
                vfloat4 sv;
                sv.x = (hit && mjv == 0) ? sval : 0.f;
                sv.y = (hit && mjv == 1) ? sval : 0.f;
                sv.z = (hit && mjv == 2) ? sval : 0.f;
                sv.w = (hit && mjv == 3) ? sval : 0.f;
                sout[lane + 64 * r] = sv;
            }
        }
    }
}

extern "C" void kernel_launch(void* const* d_in, const int* in_sizes, int n_in,
                              void* d_out, int out_size, void* d_ws, size_t ws_size,
                              hipStream_t stream) {
    const float* x_cat = (const float*)d_in[0];
    const float* noise = (const float*)d_in[1];
    float* out = (float*)d_out;

    // 2048 blocks x 256 threads = 8192 waves; wave w -> 32 KB (2 tiles).
    // 32 dwordx4 stores per thread = full 268.4 MB output, one dispatch.
    fused_sampler<<<dim3(2048), dim3(256), 0, stream>>>(x_cat, noise, out);
}